// Round 1
// 599.984 us; speedup vs baseline: 1.1932x; 1.1932x over previous
//
#include <hip/hip_runtime.h>
#include <stdint.h>

// Problem constants
#define M_DIM 4096
#define K_DIM 4096
#define N_DIM 11008
#define N_GROUPS 32   // K_DIM / 128

typedef __attribute__((ext_vector_type(8))) short short8;   // 8 bf16 bit-patterns (4 VGPRs)
typedef __attribute__((ext_vector_type(4))) float floatx4;  // MFMA accumulator

__device__ __forceinline__ unsigned short f32_to_bf16(float f) {
    unsigned int u = __float_as_uint(f);
    unsigned int rounding = 0x7FFFu + ((u >> 16) & 1u);  // RNE
    return (unsigned short)((u + rounding) >> 16);
}

// ---------------------------------------------------------------------------
// Mt[i][j] = M[j][i] where M = H*diag(s2)*H*diag(s1) applied to x:
// z_i = sum_j M^T[i,j] x_j ; Mt[i][j] = s1[j]/128 * sum_a (-1)^(popc(i&a)+popc(a&j)) s2[a]
__global__ __launch_bounds__(128) void make_M_kernel(
    const float* __restrict__ signs1, const float* __restrict__ signs2,
    unsigned short* __restrict__ Mt)   // [128][128] bf16
{
    const int i = blockIdx.x;    // z-column
    const int j = threadIdx.x;   // x-row
    __shared__ float s2s[128];
    s2s[j] = signs2[j];
    __syncthreads();
    float acc = 0.f;
#pragma unroll 8
    for (int a = 0; a < 128; ++a) {
        int par = (__popc(i & a) + __popc(a & j)) & 1;
        acc += par ? -s2s[a] : s2s[a];
    }
    Mt[i * 128 + j] = f32_to_bf16(signs1[j] * acc * (1.0f / 128.0f));
}

// ---------------------------------------------------------------------------
// Z = X * M per 128-group (block-diagonal). One block: 64 rows x 1 group.
// Fuses fp32->bf16 conversion of x. MFMA 16x16x32, K=128.
#define TX_RS 136   // padded LDS row stride (shorts)

__global__ __launch_bounds__(256) void transform_x_kernel(
    const float* __restrict__ x,            // [M_DIM][K_DIM] fp32
    const unsigned short* __restrict__ Mt,  // [128][128] bf16
    unsigned short* __restrict__ z)         // [M_DIM][K_DIM] bf16
{
    __shared__ __align__(16) short Xs[64 * TX_RS];
    __shared__ __align__(16) short Ms[128 * TX_RS];

    const int tid = threadIdx.x;
    const int wave = tid >> 6, lane = tid & 63;
    const int col16 = lane & 15, quad = lane >> 4;
    const int m0 = (blockIdx.x >> 5) * 64;
    const int g = blockIdx.x & 31;
    const int c0 = g * 128;

    // stage X tile (64 x 128 fp32 -> bf16)
#pragma unroll
    for (int it = 0; it < 8; ++it) {
        int idx = tid + 256 * it;            // 2048 float4 chunks
        int row = idx >> 5, c4 = idx & 31;
        float4 v = *(const float4*)(x + (size_t)(m0 + row) * K_DIM + c0 + c4 * 4);
        uint2 o;
        o.x = (unsigned)f32_to_bf16(v.x) | ((unsigned)f32_to_bf16(v.y) << 16);
        o.y = (unsigned)f32_to_bf16(v.z) | ((unsigned)f32_to_bf16(v.w) << 16);
        *(uint2*)(Xs + row * TX_RS + c4 * 4) = o;
    }
    // stage Mt (128 x 128 bf16)
#pragma unroll
    for (int it = 0; it < 8; ++it) {
        int ch = tid + 256 * it;             // 2048 chunks of 8 shorts
        int row = ch >> 4, cc = ch & 15;
        uint4 v = *(const uint4*)(Mt + (size_t)ch * 8);
        *(uint4*)(Ms + row * TX_RS + cc * 8) = v;
    }
    __syncthreads();

    floatx4 acc[8] = {};
#pragma unroll
    for (int ks = 0; ks < 4; ++ks) {
        short8 af = *(const short8*)(Xs + (wave * 16 + col16) * TX_RS + ks * 32 + quad * 8);
#pragma unroll
        for (int ni = 0; ni < 8; ++ni) {
            short8 bf = *(const short8*)(Ms + (ni * 16 + col16) * TX_RS + ks * 32 + quad * 8);
            acc[ni] = __builtin_amdgcn_mfma_f32_16x16x32_bf16(af, bf, acc[ni], 0, 0, 0);
        }
    }
    // write z (C/D layout: col=lane&15, row=quad*4+r)
#pragma unroll
    for (int ni = 0; ni < 8; ++ni)
#pragma unroll
        for (int r = 0; r < 4; ++r) {
            int row = m0 + wave * 16 + quad * 4 + r;
            z[(size_t)row * K_DIM + c0 + ni * 16 + col16] = f32_to_bf16(acc[ni][r]);
        }
}

// ---------------------------------------------------------------------------
// Dequant is a pure LUT: w'[n, g*128+j] = norms[n,g] * centroids[idx].
// One block per output row (2048 ints = 4096 elems). 8 ints/thread.
__global__ __launch_bounds__(256) void dequant_lut_kernel(
    const int* __restrict__ packed,      // [N_DIM][2048]
    const float* __restrict__ norms,     // [N_DIM][N_GROUPS]
    const float* __restrict__ centroids, // [16]
    unsigned int* __restrict__ w_out)    // [N_DIM][2048] two bf16 per uint
{
    __shared__ float2 lut[256];
    const int tid = threadIdx.x;
    lut[tid] = make_float2(centroids[tid & 15], centroids[tid >> 4]);
    __syncthreads();

    const int row = blockIdx.x;
    const int g = tid >> 3;                 // 8 threads per 64-int group
    const float nrm = norms[row * N_GROUPS + g];
    const int* prow = packed + (size_t)row * 2048 + tid * 8;
    int4 pa = *(const int4*)(prow);
    int4 pb = *(const int4*)(prow + 4);
    int v[8] = {pa.x, pa.y, pa.z, pa.w, pb.x, pb.y, pb.z, pb.w};
    unsigned o[8];
#pragma unroll
    for (int q = 0; q < 8; ++q) {
        float2 c = lut[v[q] & 255];
        o[q] = (unsigned)f32_to_bf16(c.x * nrm) | ((unsigned)f32_to_bf16(c.y * nrm) << 16);
    }
    unsigned* orow = w_out + (size_t)row * 2048 + tid * 8;
    *(uint4*)(orow)     = make_uint4(o[0], o[1], o[2], o[3]);
    *(uint4*)(orow + 4) = make_uint4(o[4], o[5], o[6], o[7]);
}

// ---------------------------------------------------------------------------
// GEMM: C[M][N] = Z[M][K] * W[N][K]^T + bias.
// 256x256 8-phase schedule (T1+T2+T3+T4+T5): 8 waves (2Mx4N), BK=64,
// double-buffered 128 KiB LDS, counted vmcnt(6), per-phase half-tile
// prefetch via global_load_lds(16B) with source-XOR chunk swizzle.
#define BM 256
#define BN 256
#define BK 64

typedef const __attribute__((address_space(1))) void* gvp_t;
typedef __attribute__((address_space(3))) void* svp_t;

#define GFENCE() asm volatile("" ::: "memory")
#define BARRIER() do { GFENCE(); __builtin_amdgcn_s_barrier(); GFENCE(); } while (0)
#define LGKM0() asm volatile("s_waitcnt lgkmcnt(0)" ::: "memory")
#define LGKM8() asm volatile("s_waitcnt lgkmcnt(8)" ::: "memory")
#define VM6()   asm volatile("s_waitcnt vmcnt(6)" ::: "memory")
#define VM4()   asm volatile("s_waitcnt vmcnt(4)" ::: "memory")
#define VM0()   asm volatile("s_waitcnt vmcnt(0)" ::: "memory")
#define PRIO1() __builtin_amdgcn_s_setprio(1)
#define PRIO0() __builtin_amdgcn_s_setprio(0)

// Read one quadrant's A frags: 4 M-frags x 2 k-slices. rb points at the
// (row0 = qhalf + wm*64 + col16) row; s0 = (quad ^ (col16&7))*8 shorts,
// the second k-slice slot is s0^32 ((4+quad)^sw == (quad^sw)^4).
__device__ __forceinline__ void read_a4(short8 (&dst)[4][2], const short* rb, int s0) {
#pragma unroll
    for (int fm = 0; fm < 4; ++fm) {
        dst[fm][0] = *(const short8*)(rb + fm * 1024 + s0);
        dst[fm][1] = *(const short8*)(rb + fm * 1024 + (s0 ^ 32));
    }
}
__device__ __forceinline__ void read_b2(short8 (&dst)[2][2], const short* rb, int s0) {
#pragma unroll
    for (int fn = 0; fn < 2; ++fn) {
        dst[fn][0] = *(const short8*)(rb + fn * 1024 + s0);
        dst[fn][1] = *(const short8*)(rb + fn * 1024 + (s0 ^ 32));
    }
}
// 16 MFMAs: one C-quadrant over K=64 (ks outer so the 8 per-ks ops are
// independent, dependent pair 8 apart).
__device__ __forceinline__ void mfma_q(floatx4 (&acc)[4][2],
                                       const short8 (&a)[4][2], const short8 (&b)[2][2]) {
#pragma unroll
    for (int ks = 0; ks < 2; ++ks)
#pragma unroll
        for (int fm = 0; fm < 4; ++fm)
#pragma unroll
            for (int fn = 0; fn < 2; ++fn)
                acc[fm][fn] = __builtin_amdgcn_mfma_f32_16x16x32_bf16(
                    a[fm][ks], b[fn][ks], acc[fm][fn], 0, 0, 0);
}

__global__ __launch_bounds__(512, 2) void gemm_bt_kernel(
    const unsigned short* __restrict__ A,   // [M_DIM][K_DIM] bf16 bits (= Z)
    const unsigned short* __restrict__ B,   // [N_DIM][K_DIM] bf16 bits (= W')
    const float* __restrict__ bias,         // [N_DIM]
    float* __restrict__ C)                  // [M_DIM][N_DIM]
{
    // LDS: A[2 buf][256][64] | B[2 buf][256][64] bf16 = 128 KiB.
    // A rows quarter-permuted: LDS quarter q holds global rows {0,128,64,192}[q]+0..63
    //   so A-half h (LDS rows h*128..h*128+127) == the qm=h rows of BOTH wm waves.
    // B rows: LDS row = qn*128 + wn*32 + fn*16 + col16 (qn-half major).
    // => each phase's quadrant reads exactly one A-half / B-half; halves die
    //    in order h0A,h0B (ph1), h1A (ph2), h1B (ph3) -> staggered prefetch slots.
    __shared__ __align__(16) short smem[65536];
    short* As = smem;              // + buf*16384 (shorts)
    short* Bs = smem + 32768;

    const int tid = threadIdx.x;
    const int w = tid >> 6, lane = tid & 63;
    const int wm = w >> 2, wn = w & 3;          // 2 x 4 wave grid
    const int col16 = lane & 15, quad = lane >> 4;

    // XCD-bijective swizzle: 688 = 8*86 exact. mt-pair inner so both users of
    // a B-panel run adjacently on the same XCD.
    const int bid = blockIdx.x;
    const int xcd = bid & 7, idx = bid >> 3;
    const int mt = xcd * 2 + (idx & 1);         // 0..15
    const int nt = idx >> 1;                    // 0..42
    const int m0 = mt * BM, n0 = nt * BN;

    // Staging: each global_load_lds = 512 lanes x 16B = 64 rows x 128B, linear
    // LDS dest; source column chunk XOR-swizzled so ds_read slot ^ (row&7)
    // recovers it (same scheme as previous kernel: measured 0 bank conflicts).
    const int gc = (lane & 7) ^ (lane >> 3);
    const unsigned short* aSrc = A + (size_t)(m0 + w * 8 + (lane >> 3)) * K_DIM + gc * 8;
    const unsigned short* bSrc = B + (size_t)(n0 + (w >> 2) * 64 + (w & 3) * 8 + (lane >> 3)) * K_DIM + gc * 8;
    const int wOff = w * 512;                   // wave's LDS short offset within a 64-row block

#define STAGE_A(BUF, H, KT) do { \
    __builtin_amdgcn_global_load_lds((gvp_t)(aSrc + (size_t)((H) * 64) * K_DIM + (KT) * 64), \
        (svp_t)(As + (BUF) * 16384 + (H) * 8192 + wOff), 16, 0, 0); \
    __builtin_amdgcn_global_load_lds((gvp_t)(aSrc + (size_t)((H) * 64 + 128) * K_DIM + (KT) * 64), \
        (svp_t)(As + (BUF) * 16384 + (H) * 8192 + 4096 + wOff), 16, 0, 0); \
} while (0)
#define STAGE_B(BUF, H, KT) do { \
    __builtin_amdgcn_global_load_lds((gvp_t)(bSrc + (size_t)((H) * 32) * K_DIM + (KT) * 64), \
        (svp_t)(Bs + (BUF) * 16384 + (H) * 8192 + wOff), 16, 0, 0); \
    __builtin_amdgcn_global_load_lds((gvp_t)(bSrc + (size_t)((H) * 32 + 128) * K_DIM + (KT) * 64), \
        (svp_t)(Bs + (BUF) * 16384 + (H) * 8192 + 4096 + wOff), 16, 0, 0); \
} while (0)

    // Fragment-read bases (loop-invariant; buf/qm add compile-time offsets).
    const short* aR = As + (wm * 64 + col16) * 64;
    const short* bR = Bs + (wn * 32 + col16) * 64;
    const int s0 = (quad ^ (col16 & 7)) << 3;

    short8 a0[4][2], a1[4][2], b0[2][2], b1[2][2];
    floatx4 acc[2][2][4][2];   // [qm][qn][fm][fn]
#pragma unroll
    for (int i0 = 0; i0 < 2; ++i0)
#pragma unroll
        for (int i1 = 0; i1 < 2; ++i1)
#pragma unroll
            for (int i2 = 0; i2 < 4; ++i2)
#pragma unroll
                for (int i3 = 0; i3 < 2; ++i3)
                    acc[i0][i1][i2][i3] = (floatx4)0.0f;

    // Prologue: tile0 fully into buf0; 3 halves of tile1 into buf1.
    // Leaves 6 loads (3 half-tiles) in flight = steady state.
    STAGE_A(0, 0, 0); STAGE_B(0, 0, 0); STAGE_A(0, 1, 0); STAGE_B(0, 1, 0);
    VM4();
    STAGE_A(1, 0, 1); STAGE_B(1, 0, 1); STAGE_A(1, 1, 1);
    VM6();
    BARRIER();

    // Main loop: iteration i computes K-tiles t=2i (buf0) and t+1 (buf1).
    // Stage schedule (target region's last ds_read is >=1 barrier-pair earlier):
    //  ph1: buf1.B.h1<-t+1 (last read prev ph7)   ph5: buf0.B.h1<-t+2 (ph3)
    //  ph2: buf0.A.h0<-t+2 (ph1)                  ph6: buf1.A.h0<-t+3 (ph5)
    //  ph3: buf0.B.h0<-t+2 (ph1)                  ph7: buf1.B.h0<-t+3 (ph5)
    //  ph4: buf0.A.h1<-t+2 (ph2), vmcnt(6)        ph8: buf1.A.h1<-t+3 (ph6), vmcnt(6)
    // vmcnt(6) at ph4 proves tile t+1 landed before ph5 reads buf1; at ph8
    // proves t+2 landed before next-iter ph1 reads buf0.
    const int NIT = K_DIM / (2 * BK) - 1;   // 31 full iterations + peeled drain
    for (int i = 0; i < NIT; ++i) {
        const int t = 2 * i;
        // ph1: Q(0,0) on buf0
        read_a4(a0, aR, s0); read_b2(b0, bR, s0);
        STAGE_B(1, 1, t + 1);
        LGKM8();
        BARRIER(); LGKM0();
        PRIO1(); mfma_q(acc[0][0], a0, b0); PRIO0();
        BARRIER();
        // ph2: Q(1,0)
        read_a4(a1, aR + 8192, s0);
        STAGE_A(0, 0, t + 2);
        BARRIER(); LGKM0();
        PRIO1(); mfma_q(acc[1][0], a1, b0); PRIO0();
        BARRIER();
        // ph3: Q(0,1)
        read_b2(b1, bR + 8192, s0);
        STAGE_B(0, 0, t + 2);
        BARRIER(); LGKM0();
        PRIO1(); mfma_q(acc[0][1], a0, b1); PRIO0();
        BARRIER();
        // ph4: Q(1,1)
        STAGE_A(0, 1, t + 2);
        VM6();
        BARRIER();
        PRIO1(); mfma_q(acc[1][1], a1, b1); PRIO0();
        BARRIER();
        // ph5: Q(0,0) on buf1
        read_a4(a0, aR + 16384, s0); read_b2(b0, bR + 16384, s0);
        STAGE_B(0, 1, t + 2);
        LGKM8();
        BARRIER(); LGKM0();
        PRIO1(); mfma_q(acc[0][0], a0, b0); PRIO0();
        BARRIER();
        // ph6: Q(1,0)
        read_a4(a1, aR + 16384 + 8192, s0);
        STAGE_A(1, 0, t + 3);
        BARRIER(); LGKM0();
        PRIO1(); mfma_q(acc[1][0], a1, b0); PRIO0();
        BARRIER();
        // ph7: Q(0,1)
        read_b2(b1, bR + 16384 + 8192, s0);
        STAGE_B(1, 0, t + 3);
        BARRIER(); LGKM0();
        PRIO1(); mfma_q(acc[0][1], a0, b1); PRIO0();
        BARRIER();
        // ph8: Q(1,1)
        STAGE_A(1, 1, t + 3);
        VM6();
        BARRIER();
        PRIO1(); mfma_q(acc[1][1], a1, b1); PRIO0();
        BARRIER();
    }

    // Peeled drain iteration: tiles 62 (buf0), 63 (buf1); no further prefetch.
    read_a4(a0, aR, s0); read_b2(b0, bR, s0);
    STAGE_B(1, 1, 63);                      // last half of tile 63
    BARRIER(); LGKM0();
    mfma_q(acc[0][0], a0, b0);
    BARRIER();
    read_a4(a1, aR + 8192, s0);
    BARRIER(); LGKM0();
    mfma_q(acc[1][0], a1, b0);
    BARRIER();
    read_b2(b1, bR + 8192, s0);
    BARRIER(); LGKM0();
    mfma_q(acc[0][1], a0, b1);
    BARRIER();
    VM0();                                   // tile 63 fully landed
    BARRIER();
    mfma_q(acc[1][1], a1, b1);
    // phases 5-8 on buf1: no pending LDS writes remain -> no barriers needed
    read_a4(a0, aR + 16384, s0); read_b2(b0, bR + 16384, s0);
    mfma_q(acc[0][0], a0, b0);
    read_a4(a1, aR + 16384 + 8192, s0);
    mfma_q(acc[1][0], a1, b0);
    read_b2(b1, bR + 16384 + 8192, s0);
    mfma_q(acc[0][1], a0, b1);
    mfma_q(acc[1][1], a1, b1);

#undef STAGE_A
#undef STAGE_B

    // Epilogue: bias + direct stores (scalar f32; 4 rows x 64B per wave-inst,
    // fn pair completes each 128B line back-to-back for L2 write-combine).
    float bv[2][2];
#pragma unroll
    for (int qn = 0; qn < 2; ++qn)
#pragma unroll
        for (int fn = 0; fn < 2; ++fn)
            bv[qn][fn] = bias[n0 + wn * 64 + qn * 32 + fn * 16 + col16];

#pragma unroll
    for (int qm = 0; qm < 2; ++qm)
#pragma unroll
        for (int fm = 0; fm < 4; ++fm)
#pragma unroll
            for (int r = 0; r < 4; ++r) {
                float* crow = C + (size_t)(m0 + wm * 128 + qm * 64 + fm * 16 + quad * 4 + r) * N_DIM
                              + n0 + wn * 64 + col16;
#pragma unroll
                for (int qn = 0; qn < 2; ++qn)
#pragma unroll
                    for (int fn = 0; fn < 2; ++fn)
                        crow[qn * 32 + fn * 16] = acc[qm][qn][fm][fn][r] + bv[qn][fn];
            }
}

// ---------------------------------------------------------------------------
extern "C" void kernel_launch(void* const* d_in, const int* in_sizes, int n_in,
                              void* d_out, int out_size, void* d_ws, size_t ws_size,
                              hipStream_t stream) {
    const float* x        = (const float*)d_in[0];  // [4096][4096]
    const int* packed     = (const int*)d_in[1];    // [11008][2048]
    const float* norms    = (const float*)d_in[2];  // [11008][32]
    const float* centroids= (const float*)d_in[3];  // [16]
    const float* signs1   = (const float*)d_in[4];  // [128]
    const float* signs2   = (const float*)d_in[5];  // [128]
    const float* bias     = (const float*)d_in[6];  // [11008]
    float* out            = (float*)d_out;          // [4096][11008]

    // Workspace: Mt (32 KB) | w_bf16 (90.2 MB) | z_bf16 (33.6 MB)
    unsigned short* Mt     = (unsigned short*)d_ws;
    unsigned short* w_bf16 = (unsigned short*)((char*)d_ws + 32768);
    unsigned short* z_bf16 = (unsigned short*)((char*)d_ws + 32768 + (size_t)N_DIM * K_DIM * 2);

    make_M_kernel<<<128, 128, 0, stream>>>(signs1, signs2, Mt);

    transform_x_kernel<<<(M_DIM / 64) * N_GROUPS, 256, 0, stream>>>(x, Mt, z_bf16);

    dequant_lut_kernel<<<N_DIM, 256, 0, stream>>>(
        packed, norms, centroids, (unsigned int*)w_bf16);

    gemm_bt_kernel<<<dim3((M_DIM / BM) * (N_DIM / BN)), 512, 0, stream>>>(
        z_bf16, w_bf16, bias, out);
}

// Round 3
// 593.849 us; speedup vs baseline: 1.2055x; 1.0103x over previous
//
#include <hip/hip_runtime.h>
#include <stdint.h>

// Problem constants
#define M_DIM 4096
#define K_DIM 4096
#define N_DIM 11008
#define N_GROUPS 32   // K_DIM / 128

typedef __attribute__((ext_vector_type(8))) short short8;   // 8 bf16 bit-patterns (4 VGPRs)
typedef __attribute__((ext_vector_type(4))) float floatx4;  // MFMA accumulator

__device__ __forceinline__ unsigned short f32_to_bf16(float f) {
    unsigned int u = __float_as_uint(f);
    unsigned int rounding = 0x7FFFu + ((u >> 16) & 1u);  // RNE
    return (unsigned short)((u + rounding) >> 16);
}

// ---------------------------------------------------------------------------
// Mt[i][j] = M[j][i] where M = H*diag(s2)*H*diag(s1) applied to x:
// z_i = sum_j M^T[i,j] x_j ; Mt[i][j] = s1[j]/128 * sum_a (-1)^(popc(i&a)+popc(a&j)) s2[a]
__global__ __launch_bounds__(128) void make_M_kernel(
    const float* __restrict__ signs1, const float* __restrict__ signs2,
    unsigned short* __restrict__ Mt)   // [128][128] bf16
{
    const int i = blockIdx.x;    // z-column
    const int j = threadIdx.x;   // x-row
    __shared__ float s2s[128];
    s2s[j] = signs2[j];
    __syncthreads();
    float acc = 0.f;
#pragma unroll 8
    for (int a = 0; a < 128; ++a) {
        int par = (__popc(i & a) + __popc(a & j)) & 1;
        acc += par ? -s2s[a] : s2s[a];
    }
    Mt[i * 128 + j] = f32_to_bf16(signs1[j] * acc * (1.0f / 128.0f));
}

// ---------------------------------------------------------------------------
// Z = X * M per 128-group (block-diagonal). One block: 64 rows x 1 group.
// Fuses fp32->bf16 conversion of x. MFMA 16x16x32, K=128.
#define TX_RS 136   // padded LDS row stride (shorts)

__global__ __launch_bounds__(256) void transform_x_kernel(
    const float* __restrict__ x,            // [M_DIM][K_DIM] fp32
    const unsigned short* __restrict__ Mt,  // [128][128] bf16
    unsigned short* __restrict__ z)         // [M_DIM][K_DIM] bf16
{
    __shared__ __align__(16) short Xs[64 * TX_RS];
    __shared__ __align__(16) short Ms[128 * TX_RS];

    const int tid = threadIdx.x;
    const int wave = tid >> 6, lane = tid & 63;
    const int col16 = lane & 15, quad = lane >> 4;
    const int m0 = (blockIdx.x >> 5) * 64;
    const int g = blockIdx.x & 31;
    const int c0 = g * 128;

    // stage X tile (64 x 128 fp32 -> bf16)
#pragma unroll
    for (int it = 0; it < 8; ++it) {
        int idx = tid + 256 * it;            // 2048 float4 chunks
        int row = idx >> 5, c4 = idx & 31;
        float4 v = *(const float4*)(x + (size_t)(m0 + row) * K_DIM + c0 + c4 * 4);
        uint2 o;
        o.x = (unsigned)f32_to_bf16(v.x) | ((unsigned)f32_to_bf16(v.y) << 16);
        o.y = (unsigned)f32_to_bf16(v.z) | ((unsigned)f32_to_bf16(v.w) << 16);
        *(uint2*)(Xs + row * TX_RS + c4 * 4) = o;
    }
    // stage Mt (128 x 128 bf16)
#pragma unroll
    for (int it = 0; it < 8; ++it) {
        int ch = tid + 256 * it;             // 2048 chunks of 8 shorts
        int row = ch >> 4, cc = ch & 15;
        uint4 v = *(const uint4*)(Mt + (size_t)ch * 8);
        *(uint4*)(Ms + row * TX_RS + cc * 8) = v;
    }
    __syncthreads();

    floatx4 acc[8] = {};
#pragma unroll
    for (int ks = 0; ks < 4; ++ks) {
        short8 af = *(const short8*)(Xs + (wave * 16 + col16) * TX_RS + ks * 32 + quad * 8);
#pragma unroll
        for (int ni = 0; ni < 8; ++ni) {
            short8 bf = *(const short8*)(Ms + (ni * 16 + col16) * TX_RS + ks * 32 + quad * 8);
            acc[ni] = __builtin_amdgcn_mfma_f32_16x16x32_bf16(af, bf, acc[ni], 0, 0, 0);
        }
    }
    // write z (C/D layout: col=lane&15, row=quad*4+r)
#pragma unroll
    for (int ni = 0; ni < 8; ++ni)
#pragma unroll
        for (int r = 0; r < 4; ++r) {
            int row = m0 + wave * 16 + quad * 4 + r;
            z[(size_t)row * K_DIM + c0 + ni * 16 + col16] = f32_to_bf16(acc[ni][r]);
        }
}

// ---------------------------------------------------------------------------
// Dequant is a pure LUT: w'[n, g*128+j] = norms[n,g] * centroids[idx].
// One block per output row (2048 ints = 4096 elems). 8 ints/thread.
__global__ __launch_bounds__(256) void dequant_lut_kernel(
    const int* __restrict__ packed,      // [N_DIM][2048]
    const float* __restrict__ norms,     // [N_DIM][N_GROUPS]
    const float* __restrict__ centroids, // [16]
    unsigned int* __restrict__ w_out)    // [N_DIM][2048] two bf16 per uint
{
    __shared__ float2 lut[256];
    const int tid = threadIdx.x;
    lut[tid] = make_float2(centroids[tid & 15], centroids[tid >> 4]);
    __syncthreads();

    const int row = blockIdx.x;
    const int g = tid >> 3;                 // 8 threads per 64-int group
    const float nrm = norms[row * N_GROUPS + g];
    const int* prow = packed + (size_t)row * 2048 + tid * 8;
    int4 pa = *(const int4*)(prow);
    int4 pb = *(const int4*)(prow + 4);
    int v[8] = {pa.x, pa.y, pa.z, pa.w, pb.x, pb.y, pb.z, pb.w};
    unsigned o[8];
#pragma unroll
    for (int q = 0; q < 8; ++q) {
        float2 c = lut[v[q] & 255];
        o[q] = (unsigned)f32_to_bf16(c.x * nrm) | ((unsigned)f32_to_bf16(c.y * nrm) << 16);
    }
    unsigned* orow = w_out + (size_t)row * 2048 + tid * 8;
    *(uint4*)(orow)     = make_uint4(o[0], o[1], o[2], o[3]);
    *(uint4*)(orow + 4) = make_uint4(o[4], o[5], o[6], o[7]);
}

// ---------------------------------------------------------------------------
// GEMM: C[M][N] = Z[M][K] * W[N][K]^T + bias.
// 256x256 8-phase schedule, R2 revision: ds_reads for phase p+1 issued INSIDE
// phase p's MFMA region (one barrier per phase), so the LDS pipe runs under
// the matrix pipe instead of alternating with it. Uniform vmcnt(8) keeps 4
// half-tiles in flight (stage->read gap = 4-5 phases, covers HBM latency).
#define BM 256
#define BN 256
#define BK 64

typedef const __attribute__((address_space(1))) void* gvp_t;
typedef __attribute__((address_space(3))) void* svp_t;

#define BARRIER() do { asm volatile("" ::: "memory"); __builtin_amdgcn_s_barrier(); \
                       asm volatile("" ::: "memory"); } while (0)
#define VM8()   asm volatile("s_waitcnt vmcnt(8)" ::: "memory")
#define VM4()   asm volatile("s_waitcnt vmcnt(4)" ::: "memory")
#define VM2()   asm volatile("s_waitcnt vmcnt(2)" ::: "memory")
#define VM0()   asm volatile("s_waitcnt vmcnt(0)" ::: "memory")
#define PRIO1() __builtin_amdgcn_s_setprio(1)
#define PRIO0() __builtin_amdgcn_s_setprio(0)

// Read one quadrant's A frags: 4 M-frags x 2 k-slices. rb points at the
// (row0 = qhalf + wm*64 + col16) row; s0 = (quad ^ (col16&7))*8 shorts,
// the second k-slice slot is s0^32 ((4+quad)^sw == (quad^sw)^4).
__device__ __forceinline__ void read_a4(short8 (&dst)[4][2], const short* rb, int s0) {
#pragma unroll
    for (int fm = 0; fm < 4; ++fm) {
        dst[fm][0] = *(const short8*)(rb + fm * 1024 + s0);
        dst[fm][1] = *(const short8*)(rb + fm * 1024 + (s0 ^ 32));
    }
}
__device__ __forceinline__ void read_b2(short8 (&dst)[2][2], const short* rb, int s0) {
#pragma unroll
    for (int fn = 0; fn < 2; ++fn) {
        dst[fn][0] = *(const short8*)(rb + fn * 1024 + s0);
        dst[fn][1] = *(const short8*)(rb + fn * 1024 + (s0 ^ 32));
    }
}
// 16 MFMAs: one C-quadrant over K=64 (ks outer so the 8 per-ks ops are
// independent, dependent pair 8 apart).
__device__ __forceinline__ void mfma_q(floatx4 (&acc)[4][2],
                                       const short8 (&a)[4][2], const short8 (&b)[2][2]) {
#pragma unroll
    for (int ks = 0; ks < 2; ++ks)
#pragma unroll
        for (int fm = 0; fm < 4; ++fm)
#pragma unroll
            for (int fn = 0; fn < 2; ++fn)
                acc[fm][fn] = __builtin_amdgcn_mfma_f32_16x16x32_bf16(
                    a[fm][ks], b[fn][ks], acc[fm][fn], 0, 0, 0);
}

__global__ __launch_bounds__(512, 2) void gemm_bt_kernel(
    const unsigned short* __restrict__ A,   // [M_DIM][K_DIM] bf16 bits (= Z)
    const unsigned short* __restrict__ B,   // [N_DIM][K_DIM] bf16 bits (= W')
    const float* __restrict__ bias,         // [N_DIM]
    float* __restrict__ C)                  // [M_DIM][N_DIM]
{
    // LDS: A[2 buf][256][64] | B[2 buf][256][64] bf16 = 128 KiB.
    // A rows quarter-permuted: LDS quarter q holds global rows {0,128,64,192}[q]+0..63
    //   so A-half h (LDS rows h*128..h*128+127) == the qm=h rows of BOTH wm waves.
    // B rows: LDS row = qn*128 + wn*32 + fn*16 + col16 (qn-half major).
    __shared__ __align__(16) short smem[65536];
    short* As = smem;              // + buf*16384 (shorts)
    short* Bs = smem + 32768;

    const int tid = threadIdx.x;
    const int w = tid >> 6, lane = tid & 63;
    const int wm = w >> 2, wn = w & 3;          // 2 x 4 wave grid
    const int col16 = lane & 15, quad = lane >> 4;

    // nt-major grid order, NO xcd swizzle: hw round-robin (bid%8) then pins
    // each XCD to 2 fixed A-panels (4 MB, L2-resident) while the ~16 active
    // B-panels (32 MB) get 16 consumers each inside the shared L3 window.
    const int bid = blockIdx.x;
    const int mt = bid & 15;                    // 0..15 (M/BM = 16 exactly)
    const int nt = bid >> 4;                    // 0..42
    const int m0 = mt * BM, n0 = nt * BN;

    // Staging: each global_load_lds = 512 lanes x 16B = 64 rows x 128B, linear
    // LDS dest; source column chunk XOR-swizzled so ds_read slot ^ (row&7)
    // recovers it (measured 0 bank conflicts).
    const int gc = (lane & 7) ^ (lane >> 3);
    const unsigned short* aSrc = A + (size_t)(m0 + w * 8 + (lane >> 3)) * K_DIM + gc * 8;
    const unsigned short* bSrc = B + (size_t)(n0 + (w >> 2) * 64 + (w & 3) * 8 + (lane >> 3)) * K_DIM + gc * 8;
    const int wOff = w * 512;                   // wave's LDS short offset within a 64-row block

#define STAGE_A(BUF, H, KT) do { \
    __builtin_amdgcn_global_load_lds((gvp_t)(aSrc + (size_t)((H) * 64) * K_DIM + (KT) * 64), \
        (svp_t)(As + (BUF) * 16384 + (H) * 8192 + wOff), 16, 0, 0); \
    __builtin_amdgcn_global_load_lds((gvp_t)(aSrc + (size_t)((H) * 64 + 128) * K_DIM + (KT) * 64), \
        (svp_t)(As + (BUF) * 16384 + (H) * 8192 + 4096 + wOff), 16, 0, 0); \
} while (0)
#define STAGE_B(BUF, H, KT) do { \
    __builtin_amdgcn_global_load_lds((gvp_t)(bSrc + (size_t)((H) * 32) * K_DIM + (KT) * 64), \
        (svp_t)(Bs + (BUF) * 16384 + (H) * 8192 + wOff), 16, 0, 0); \
    __builtin_amdgcn_global_load_lds((gvp_t)(bSrc + (size_t)((H) * 32 + 128) * K_DIM + (KT) * 64), \
        (svp_t)(Bs + (BUF) * 16384 + (H) * 8192 + 4096 + wOff), 16, 0, 0); \
} while (0)

    // Fragment-read bases (loop-invariant; buf/half add compile-time offsets).
    const short* aR = As + (wm * 64 + col16) * 64;
    const short* bR = Bs + (wn * 32 + col16) * 64;
    const int s0 = (quad ^ (col16 & 7)) << 3;

    short8 a0[4][2], a1[4][2], b0[2][2], b1[2][2];
    floatx4 acc[2][2][4][2];   // [qm][qn][fm][fn]
#pragma unroll
    for (int i0 = 0; i0 < 2; ++i0)
#pragma unroll
        for (int i1 = 0; i1 < 2; ++i1)
#pragma unroll
            for (int i2 = 0; i2 < 4; ++i2)
#pragma unroll
                for (int i3 = 0; i3 < 2; ++i3)
                    acc[i0][i1][i2][i3] = (floatx4)0.0f;

    // ------------------------------------------------------------------
    // SYNC LEDGER (one barrier per phase, vmcnt BEFORE barrier publishes):
    //  Stage schedule per iter i (t=2i):
    //   ph1: B1.h1<-t+1  ph2: A0.h0<-t+2  ph3: B0.h0<-t+2  ph4: A0.h1<-t+2
    //   ph5: B0.h1<-t+2  ph6: A1.h0<-t+3  ph7: B1.h0<-t+3  ph8: A1.h1<-t+3
    //  Reads (issued in phase p, consumed by MFMA of p+1):
    //   ph1: a1<-buf0.A.h1(t)     [staged prev ph4; pub by prev ph8 VM8+bar]
    //   ph2: b1<-buf0.B.h1(t)     [prev ph5; pub by ph1 VM8+bar]
    //   ph4: a0,b0<-buf1.h0(t+1)  [prev ph6/ph7; pub by ph3 VM8+bar]
    //   ph5: a1<-buf1.A.h1(t+1)   [prev ph8; pub by ph4 VM8+bar]
    //   ph6: b1<-buf1.B.h1(t+1)   [ph1; pub by ph5 VM8+bar]
    //   ph8: a0,b0<-buf0.h0(t+2)  [ph2/ph3; pub by ph7 VM8+bar]
    //  Each VM8 leaves exactly the newest 4 half-tiles outstanding; the
    //  required stage is always the oldest drained one (exact, verified).
    //  WAR: every stage is issued >=2 phases after the last read-issue of its
    //  region; the read's MFMA-use (and its compiler lgkm wait) precedes the
    //  intervening barrier, so reads complete before any stage-issue.
    // ------------------------------------------------------------------

    // Prologue = stages of virtual phases 2..7, then ph8 role.
    STAGE_A(0, 0, 0); STAGE_B(0, 0, 0);     // ph2,ph3 (t=0)
    STAGE_A(0, 1, 0); STAGE_B(0, 1, 0);     // ph4,ph5
    STAGE_A(1, 0, 1); STAGE_B(1, 0, 1);     // ph6,ph7
    VM8();                                   // oldest 4 (buf0.h0) landed
    BARRIER();
    // ph8 role: read buf0.h0, stage A1.h1(1)
    read_a4(a0, aR, s0); read_b2(b0, bR, s0);
    STAGE_A(1, 1, 1);
    VM8();                                   // through A0.h1 landed (for ph1's a1)
    BARRIER();

    const int NIT = K_DIM / (2 * BK) - 1;   // 31 full iterations + drain
    for (int i = 0; i < NIT; ++i) {
        const int t = 2 * i;
        // ph1: Q00(a0,b0) | reads a1 | stage B1.h1 | VM8
        read_a4(a1, aR + 8192, s0);
        PRIO1(); mfma_q(acc[0][0], a0, b0); PRIO0();
        STAGE_B(1, 1, t + 1);
        VM8(); BARRIER();
        // ph2: Q10(a1,b0) | reads b1 | stage A0.h0
        read_b2(b1, bR + 8192, s0);
        PRIO1(); mfma_q(acc[1][0], a1, b0); PRIO0();
        STAGE_A(0, 0, t + 2);
        BARRIER();
        // ph3: Q01(a0,b1) | stage B0.h0 | VM8
        PRIO1(); mfma_q(acc[0][1], a0, b1); PRIO0();
        STAGE_B(0, 0, t + 2);
        VM8(); BARRIER();
        // ph4: Q11(a1,b1) | reads a0,b0 <- buf1.h0 | stage A0.h1 | VM8
        read_a4(a0, aR + 16384, s0); read_b2(b0, bR + 16384, s0);
        PRIO1(); mfma_q(acc[1][1], a1, b1); PRIO0();
        STAGE_A(0, 1, t + 2);
        VM8(); BARRIER();
        // ph5: Q00(a0,b0) buf1 | reads a1 | stage B0.h1 | VM8
        read_a4(a1, aR + 16384 + 8192, s0);
        PRIO1(); mfma_q(acc[0][0], a0, b0); PRIO0();
        STAGE_B(0, 1, t + 2);
        VM8(); BARRIER();
        // ph6: Q10(a1,b0) | reads b1 | stage A1.h0
        read_b2(b1, bR + 16384 + 8192, s0);
        PRIO1(); mfma_q(acc[1][0], a1, b0); PRIO0();
        STAGE_A(1, 0, t + 3);
        BARRIER();
        // ph7: Q01(a0,b1) | stage B1.h0 | VM8
        PRIO1(); mfma_q(acc[0][1], a0, b1); PRIO0();
        STAGE_B(1, 0, t + 3);
        VM8(); BARRIER();
        // ph8: Q11(a1,b1) | reads a0,b0 <- buf0.h0(t+2) | stage A1.h1 | VM8
        read_a4(a0, aR, s0); read_b2(b0, bR, s0);
        PRIO1(); mfma_q(acc[1][1], a1, b1); PRIO0();
        STAGE_A(1, 1, t + 3);
        VM8(); BARRIER();
    }

    // Drain: buf0 = t=62, buf1 = t=63 (B1.h1 of 63 staged at dph1).
    // dph1
    read_a4(a1, aR + 8192, s0);
    mfma_q(acc[0][0], a0, b0);
    STAGE_B(1, 1, 63);
    VM8();                                   // through B0.h1(62): dph2's b1
    BARRIER();
    // dph2
    read_b2(b1, bR + 8192, s0);
    mfma_q(acc[1][0], a1, b0);
    VM4();                                   // through B1.h0(63): dph4's a0,b0
    BARRIER();
    // dph3
    mfma_q(acc[0][1], a0, b1);
    VM2();                                   // through A1.h1(63): dph5's a1
    BARRIER();
    // dph4
    read_a4(a0, aR + 16384, s0); read_b2(b0, bR + 16384, s0);
    mfma_q(acc[1][1], a1, b1);
    VM0();                                   // through B1.h1(63): dph6's b1
    BARRIER();
    // dph5..dph8: no pending stages -> no more barriers needed
    read_a4(a1, aR + 16384 + 8192, s0);
    mfma_q(acc[0][0], a0, b0);
    read_b2(b1, bR + 16384 + 8192, s0);
    mfma_q(acc[1][0], a1, b0);
    mfma_q(acc[0][1], a0, b1);
    mfma_q(acc[1][1], a1, b1);

#undef STAGE_A
#undef STAGE_B

    // Epilogue: bias + direct stores (fn pair completes each 128B line
    // back-to-back for L2 write-combine).
    float bv[2][2];
#pragma unroll
    for (int qn = 0; qn < 2; ++qn)
#pragma unroll
        for (int fn = 0; fn < 2; ++fn)
            bv[qn][fn] = bias[n0 + wn * 64 + qn * 32 + fn * 16 + col16];

#pragma unroll
    for (int qm = 0; qm < 2; ++qm)
#pragma unroll
        for (int fm = 0; fm < 4; ++fm)
#pragma unroll
            for (int r = 0; r < 4; ++r) {
                float* crow = C + (size_t)(m0 + wm * 128 + qm * 64 + fm * 16 + quad * 4 + r) * N_DIM
                              + n0 + wn * 64 + col16;
#pragma unroll
                for (int qn = 0; qn < 2; ++qn)
#pragma unroll
                    for (int fn = 0; fn < 2; ++fn)
                        crow[qn * 32 + fn * 16] = acc[qm][qn][fm][fn][r] + bv[qn][fn];
            }
}

// ---------------------------------------------------------------------------
extern "C" void kernel_launch(void* const* d_in, const int* in_sizes, int n_in,
                              void* d_out, int out_size, void* d_ws, size_t ws_size,
                              hipStream_t stream) {
    const float* x        = (const float*)d_in[0];  // [4096][4096]
    const int* packed     = (const int*)d_in[1];    // [11008][2048]
    const float* norms    = (const float*)d_in[2];  // [11008][32]
    const float* centroids= (const float*)d_in[3];  // [16]
    const float* signs1   = (const float*)d_in[4];  // [128]
    const float* signs2   = (const float*)d_in[5];  // [128]
    const float* bias     = (const float*)d_in[6];  // [11008]
    float* out            = (float*)d_out;          // [4096][11008]

    // Workspace: Mt (32 KB) | w_bf16 (90.2 MB) | z_bf16 (33.6 MB)
    unsigned short* Mt     = (unsigned short*)d_ws;
    unsigned short* w_bf16 = (unsigned short*)((char*)d_ws + 32768);
    unsigned short* z_bf16 = (unsigned short*)((char*)d_ws + 32768 + (size_t)N_DIM * K_DIM * 2);

    make_M_kernel<<<128, 128, 0, stream>>>(signs1, signs2, Mt);

    transform_x_kernel<<<(M_DIM / 64) * N_GROUPS, 256, 0, stream>>>(x, Mt, z_bf16);

    dequant_lut_kernel<<<N_DIM, 256, 0, stream>>>(
        packed, norms, centroids, (unsigned int*)w_bf16);

    gemm_bt_kernel<<<dim3((M_DIM / BM) * (N_DIM / BN)), 512, 0, stream>>>(
        z_bf16, w_bf16, bias, out);
}